// Round 4
// baseline (531.817 us; speedup 1.0000x reference)
//
#include <hip/hip_runtime.h>
#include <math.h>

#define N_NODES 8192
#define N_EDGES 131072
#define C 32
#define Zn 10
#define NG 16
#define NSH 9
#define NB 8
#define H 64
#define ACTW 104   // 96 cols + pad; rows 16B-aligned (104*2=208B), 2-way banks only

__device__ __forceinline__ float silu_f(float v){ return v / (1.0f + __expf(-v)); }

typedef __attribute__((ext_vector_type(8))) short bfrag_t;  // 8 bf16 (4 VGPRs)
typedef __attribute__((ext_vector_type(4))) float accv_t;   // 4 f32 acc

__device__ __forceinline__ short f2bf(float f){
  union { float f; unsigned u; } v; v.f = f;
  unsigned r = v.u + 0x7FFFu + ((v.u >> 16) & 1u);   // RNE
  return (short)(r >> 16);
}
__device__ __forceinline__ float bf2f(short s){
  union { float f; unsigned u; } v; v.u = ((unsigned)(unsigned short)s) << 16;
  return v.f;
}

// ---------------------------------------------------------------- CSR build
__global__ __launch_bounds__(256)
void hist_kernel(const int* __restrict__ ei, int* __restrict__ counts){
  int e = blockIdx.x*256 + threadIdx.x;
  atomicAdd(counts + ei[N_EDGES + e], 1);
}

__global__ __launch_bounds__(256)
void scan_kernel(const int* __restrict__ counts, int* __restrict__ row_start,
                 int* __restrict__ cursor){
  __shared__ int part[256];
  int tid = threadIdx.x;
  int base = tid*32;
  int local[32];
  int s = 0;
  #pragma unroll
  for (int i = 0; i < 32; i++){ local[i] = s; s += counts[base+i]; }
  part[tid] = s; __syncthreads();
  for (int off = 1; off < 256; off <<= 1){
    int v = (tid >= off) ? part[tid-off] : 0;
    __syncthreads();
    part[tid] += v;
    __syncthreads();
  }
  int excl = part[tid] - s;
  #pragma unroll
  for (int i = 0; i < 32; i++){
    int v = excl + local[i];
    row_start[base+i] = v;
    cursor[base+i] = v;
  }
  if (tid == 255) row_start[N_NODES] = part[255];
}

__global__ __launch_bounds__(256)
void fill_kernel(const int* __restrict__ ei, int* __restrict__ cursor,
                 int* __restrict__ order){
  int e = blockIdx.x*256 + threadIdx.x;
  int rcv = ei[N_EDGES + e];
  int pos = atomicAdd(cursor + rcv, 1);
  order[pos] = e;
}

// ---------------------------------------------------------------- species + baseline outputs
__global__ __launch_bounds__(256)
void spec_kernel(const float* __restrict__ na, const float* __restrict__ ae,
                 const float* __restrict__ charges, const float* __restrict__ pos,
                 const int* __restrict__ batch, int* __restrict__ species,
                 float* __restrict__ out){
  __shared__ float glds[NG][4];
  int tid = threadIdx.x;
  if (tid < NG*4) glds[tid>>2][tid&3] = 0.f;
  __syncthreads();
  int n = blockIdx.x*256 + tid;
  int spec = 0;
  #pragma unroll
  for (int z = 1; z < Zn; z++) if (na[n*Zn+z] > 0.5f) spec = z;
  species[n] = spec;
  int g = batch[n];
  float q = charges[n];
  atomicAdd(&glds[g][0], ae[spec]);
  atomicAdd(&glds[g][1], q*pos[n*3+0]);
  atomicAdd(&glds[g][2], q*pos[n*3+1]);
  atomicAdd(&glds[g][3], q*pos[n*3+2]);
  __syncthreads();
  if (tid < NG*4){
    float v = glds[tid>>2][tid&3];
    if (v != 0.f) atomicAdd(out + tid, v);
  }
}

__global__ __launch_bounds__(256)
void h0_kernel(const int* __restrict__ species, const float* __restrict__ Wemb,
               float* __restrict__ hg){
  int idx = blockIdx.x*256 + threadIdx.x;        // [0, N*32)
  int n = idx >> 5, c = idx & 31;
  hg[(size_t)n*288 + c] = Wemb[species[n]*C + c];
}

// ---------------------------------------------------------------- geometry (CSR-slot order)
__global__ __launch_bounds__(128)
void geom_kernel(const float* __restrict__ pos, const int* __restrict__ ei,
                 const int* __restrict__ order, int* __restrict__ snd_perm,
                 float* __restrict__ Ye, float* __restrict__ RBt){
  int t = blockIdx.x*128 + threadIdx.x;          // CSR slot
  int e = order[t];
  int snd = ei[e], rcv = ei[N_EDGES + e];
  snd_perm[t] = snd;
  float px = pos[rcv*3+0]-pos[snd*3+0];
  float py = pos[rcv*3+1]-pos[snd*3+1];
  float pz = pos[rcv*3+2]-pos[snd*3+2];
  float r2 = px*px+py*py+pz*pz + 1e-12f;
  float r = sqrtf(r2);
  float inv = 1.0f/r;
  float x = px*inv, y = py*inv, z = pz*inv;
  const float s3 = 1.7320508075688772f;
  const float s5 = 2.23606797749979f;
  const float s15 = 3.872983346207417f;
  float* ye = Ye + (size_t)t*16;
  ye[0] = 1.0f;
  ye[1] = s3*x;
  ye[2] = s3*y;
  ye[3] = s3*z;
  ye[4] = s15*x*y;
  ye[5] = s15*y*z;
  ye[6] = 0.5f*s5*(3.0f*z*z-1.0f);
  ye[7] = s15*x*z;
  ye[8] = 0.5f*s15*(x*x-y*y);
  float xr = r * 0.2f;                       // r / R_MAX
  float env = 0.0f;
  if (xr < 1.0f){
    float x2 = xr*xr;
    float x5 = x2*x2*xr;
    env = 1.0f - 21.0f*x5 + 35.0f*x5*xr - 15.0f*x5*x2;
  }
  const float pref = 0.6324555320336759f;    // sqrt(2/5)
  float sc = pref * inv * env;
  const float piOverR = 0.6283185307179586f; // pi/5
  #pragma unroll
  for (int n = 1; n <= NB; n++){
    RBt[(n-1)*N_EDGES+t] = sc * sinf((float)n * piOverR * r);
  }
}

// ---------------------------------------------------------------- edge MLP (MFMA bf16)
// frag-ordered weight LDS offsets (elements); frag = ((ntile*KS + kstep)*64 + lane)*8 + j
#define WF_L0 0        // 4 ntiles * 1 kstep * 512
#define WF_L1 2048     // 4 * 2 * 512
#define WF_L2 6144
#define WF_L3 10240    // 6 * 2 * 512
#define WF_TOT 16384

__global__ __launch_bounds__(128, 1)
void edge_kernel(const float* __restrict__ R0i, const float* __restrict__ R1i,
                 const float* __restrict__ R2i, const float* __restrict__ R3i,
                 const float* __restrict__ RBt, const float* __restrict__ hg,
                 const int* __restrict__ snd_perm, float* __restrict__ P){
  __shared__ short wf[WF_TOT];        // 32 KB
  __shared__ short act[128*ACTW];     // 26 KB
  int tid = threadIdx.x;
  int lane = tid & 63;
  int quad = lane >> 4;
  int m16  = lane & 15;
  int wbase = (tid >> 6) * 64;        // wave's edge-local base
  int eg0 = blockIdx.x * 128;         // block's global edge base

  // ---- stage weights in fragment order (bf16)
  for (int idx = tid; idx < WF_TOT; idx += 128){
    int li, u;
    if (idx < WF_L1){ u = idx;        li = 0; }
    else if (idx < WF_L2){ u = idx - WF_L1; li = 1; }
    else if (idx < WF_L3){ u = idx - WF_L2; li = 2; }
    else { u = idx - WF_L3; li = 3; }
    int sh = (li == 0) ? 9 : 10;
    int nt = u >> sh;
    int rem = u & ((1 << sh) - 1);
    int ks = rem >> 9; rem &= 511;
    int ln = rem >> 3, j = rem & 7;
    int k = ks*32 + (ln >> 4)*8 + j;
    int col = nt*16 + (ln & 15);
    float v;
    if (li == 0)      v = (k < 8) ? R0i[k*H + col] : 0.f;
    else if (li == 1) v = R1i[k*H + col];
    else if (li == 2) v = R2i[k*H + col];
    else              v = R3i[k*96 + col];
    wf[idx] = f2bf(v);
  }
  // ---- stage rb -> act cols [0,32)  (8 real, 24 zero: K padded to 32)
  {
    short* arow = act + tid*ACTW;
    #pragma unroll
    for (int k = 0; k < 8; k++) arow[k] = f2bf(RBt[k*N_EDGES + eg0 + tid]);
    #pragma unroll
    for (int k = 8; k < 32; k++) arow[k] = 0;
  }
  __syncthreads();

  // ---- layer 0: K=32 (1 kstep), N=64
  {
    bfrag_t B[4];
    #pragma unroll
    for (int n = 0; n < 4; n++)
      B[n] = *(const bfrag_t*)(wf + WF_L0 + (n*64 + lane)*8);
    accv_t acc[4][4];
    #pragma unroll
    for (int m = 0; m < 4; m++){
      bfrag_t A = *(const bfrag_t*)(act + (wbase + m*16 + m16)*ACTW + quad*8);
      #pragma unroll
      for (int n = 0; n < 4; n++){
        accv_t z = {0.f,0.f,0.f,0.f};
        acc[m][n] = __builtin_amdgcn_mfma_f32_16x16x32_bf16(A, B[n], z, 0,0,0);
      }
    }
    #pragma unroll
    for (int m = 0; m < 4; m++){
      int row = wbase + m*16 + quad*4;
      #pragma unroll
      for (int n = 0; n < 4; n++)
        #pragma unroll
        for (int r = 0; r < 4; r++)
          act[(row + r)*ACTW + n*16 + m16] = f2bf(silu_f(acc[m][n][r]));
    }
  }
  __syncthreads();

  // ---- layers 1,2: K=64 (2 ksteps), N=64
  for (int L = 0; L < 2; L++){
    const short* wfl = wf + (L == 0 ? WF_L1 : WF_L2);
    bfrag_t B[8];
    #pragma unroll
    for (int n = 0; n < 4; n++)
      #pragma unroll
      for (int s = 0; s < 2; s++)
        B[n*2+s] = *(const bfrag_t*)(wfl + ((n*2 + s)*64 + lane)*8);
    accv_t acc[4][4];
    #pragma unroll
    for (int m = 0; m < 4; m++){
      const short* ar = act + (wbase + m*16 + m16)*ACTW + quad*8;
      bfrag_t A0 = *(const bfrag_t*)(ar);
      bfrag_t A1 = *(const bfrag_t*)(ar + 32);
      #pragma unroll
      for (int n = 0; n < 4; n++){
        accv_t z = {0.f,0.f,0.f,0.f};
        z = __builtin_amdgcn_mfma_f32_16x16x32_bf16(A0, B[n*2+0], z, 0,0,0);
        z = __builtin_amdgcn_mfma_f32_16x16x32_bf16(A1, B[n*2+1], z, 0,0,0);
        acc[m][n] = z;
      }
    }
    #pragma unroll
    for (int m = 0; m < 4; m++){
      int row = wbase + m*16 + quad*4;
      #pragma unroll
      for (int n = 0; n < 4; n++)
        #pragma unroll
        for (int r = 0; r < 4; r++)
          act[(row + r)*ACTW + n*16 + m16] = f2bf(silu_f(acc[m][n][r]));
    }
    __syncthreads();
  }

  // ---- layer 3: K=64, N=96 (6 ntiles), no silu
  {
    bfrag_t B[12];
    #pragma unroll
    for (int n = 0; n < 6; n++)
      #pragma unroll
      for (int s = 0; s < 2; s++)
        B[n*2+s] = *(const bfrag_t*)(wf + WF_L3 + ((n*2 + s)*64 + lane)*8);
    accv_t acc[4][6];
    #pragma unroll
    for (int m = 0; m < 4; m++){
      const short* ar = act + (wbase + m*16 + m16)*ACTW + quad*8;
      bfrag_t A0 = *(const bfrag_t*)(ar);
      bfrag_t A1 = *(const bfrag_t*)(ar + 32);
      #pragma unroll
      for (int n = 0; n < 6; n++){
        accv_t z = {0.f,0.f,0.f,0.f};
        z = __builtin_amdgcn_mfma_f32_16x16x32_bf16(A0, B[n*2+0], z, 0,0,0);
        z = __builtin_amdgcn_mfma_f32_16x16x32_bf16(A1, B[n*2+1], z, 0,0,0);
        acc[m][n] = z;
      }
    }
    #pragma unroll
    for (int m = 0; m < 4; m++){
      int row = wbase + m*16 + quad*4;
      #pragma unroll
      for (int n = 0; n < 6; n++)
        #pragma unroll
        for (int r = 0; r < 4; r++)
          act[(row + r)*ACTW + n*16 + m16] = f2bf(acc[m][n][r]);
    }
  }
  __syncthreads();

  // ---- epilogue: P[t][96] = Rw * h_snd[col&31], per-thread row, float4 out
  {
    int tglob = eg0 + tid;
    int snd = snd_perm[tglob];
    const float4* hrow = (const float4*)(hg + (size_t)snd*288);
    float hs[32];
    #pragma unroll
    for (int q = 0; q < 8; q++){
      float4 h4 = hrow[q];
      hs[q*4+0]=h4.x; hs[q*4+1]=h4.y; hs[q*4+2]=h4.z; hs[q*4+3]=h4.w;
    }
    const short* arow = act + tid*ACTW;
    float* Prow = P + (size_t)tglob*96;
    #pragma unroll
    for (int c = 0; c < 96; c += 4){
      short4 a4 = *(const short4*)(arow + c);
      float4 v;
      v.x = bf2f(a4.x)*hs[(c+0)&31];
      v.y = bf2f(a4.y)*hs[(c+1)&31];
      v.z = bf2f(a4.z)*hs[(c+2)&31];
      v.w = bf2f(a4.w)*hs[(c+3)&31];
      *(float4*)(Prow + c) = v;
    }
  }
}

// ---------------------------------------------------------------- node: contiguous gather + mix + gate + readout
__global__ __launch_bounds__(256)
void node_kernel(const float* __restrict__ P, const float* __restrict__ Ye,
                 const int* __restrict__ row_start,
                 float* __restrict__ hg,
                 const float* __restrict__ Wm_g, const float* __restrict__ Ws_g,
                 const float* __restrict__ Wp1, const float* __restrict__ Wp2,
                 const float* __restrict__ Wp3,
                 const int* __restrict__ species, const int* __restrict__ batch,
                 const float* __restrict__ wEv, const float* __restrict__ wDv,
                 const float* __restrict__ Whg, const float* __restrict__ wE2g,
                 int iter, float* __restrict__ out){
  __shared__ float Wm[3*32*32];
  __shared__ float Ws[3*32*32];
  __shared__ float abuf[4][288];
  __shared__ float hbuf[4][288];
  __shared__ float glds[NG][4];
  int tid = threadIdx.x;
  for (int t = tid; t < 3072; t += 256){ Wm[t] = Wm_g[t]; Ws[t] = Ws_g[t]; }
  if (tid < NG*4) glds[tid>>2][tid&3] = 0.f;
  int w = tid >> 6, lane = tid & 63;
  int n = blockIdx.x*4 + w;
  for (int idx = lane; idx < 288; idx += 64){
    hbuf[w][idx] = hg[(long)n*288+idx];
  }

  // ---- gather A[m][c] = sum_{slots j of n} P[j][lmap[m]*32+c] * Ye[j][m]
  int cols[5], ms[5]; bool act5[5];
  #pragma unroll
  for (int s = 0; s < 5; s++){
    int idx = lane + s*64;
    act5[s] = (idx < 288);
    int m = act5[s] ? (idx >> 5) : 0;
    int l = (m >= 4) ? 2 : ((m >= 1) ? 1 : 0);
    cols[s] = l*32 + (idx & 31);
    ms[s] = m;
  }
  float acc[5] = {0.f,0.f,0.f,0.f,0.f};
  int jb = row_start[n], je = row_start[n+1];
  const float* Pe = P + (size_t)jb*96;
  const float* Yv = Ye + (size_t)jb*16;
  #pragma unroll 2
  for (int j = jb; j < je; j++){
    #pragma unroll
    for (int s = 0; s < 5; s++){
      if (act5[s]) acc[s] = fmaf(Pe[cols[s]], Yv[ms[s]], acc[s]);
    }
    Pe += 96; Yv += 16;
  }
  #pragma unroll
  for (int s = 0; s < 5; s++){
    int idx = lane + s*64;
    if (act5[s]) abuf[w][idx] = acc[s] * (1.0f/16.0f);
  }
  __syncthreads();

  // ---- mix: A @ W_mix[lmap], sc = h @ W_sc[lmap]
  float amv[5], scv[5];
  #pragma unroll
  for (int it = 0; it < 5; it++){
    int idx = it*64 + lane;
    amv[it] = 0.f; scv[it] = 0.f;
    if (idx < 288){
      int m = idx >> 5, d = idx & 31;
      int l = (m >= 4) ? 2 : ((m >= 1) ? 1 : 0);
      const float* wm = Wm + l*1024 + d;
      const float* ws = Ws + l*1024 + d;
      float a2 = 0.f, sc = 0.f;
      #pragma unroll
      for (int c = 0; c < 32; c++){
        a2 = fmaf(abuf[w][m*32+c], wm[c*32], a2);
        sc = fmaf(hbuf[w][m*32+c], ws[c*32], sc);
      }
      amv[it] = a2; scv[it] = sc;
    }
  }
  __syncthreads();
  #pragma unroll
  for (int it = 0; it < 5; it++){ int idx = it*64+lane; if (idx < 288) abuf[w][idx] = amv[it]; }
  __syncthreads();

  int d = lane & 31;
  float sval = abuf[w][d];
  int spec = species[n];
  float p1 = Wp1[spec*C+d], p2 = Wp2[spec*C+d], p3 = Wp3[spec*C+d];
  float f = p1 + p2*sval + p3*sval*sval;
  #pragma unroll
  for (int it = 0; it < 5; it++){
    int idx = it*64 + lane;
    if (idx < 288){
      float hn = amv[it]*f + scv[it];
      hg[(long)n*288+idx] = hn;
      hbuf[w][idx] = hn;
    }
  }
  __syncthreads();

  int g = batch[n];
  float dv0 = 0.f, dv1 = 0.f, dv2 = 0.f, ev = 0.f;
  if (lane < 32){
    dv0 = hbuf[w][32+lane]*wDv[lane];
    dv1 = hbuf[w][64+lane]*wDv[lane];
    dv2 = hbuf[w][96+lane]*wDv[lane];
  }
  if (iter == 0){
    if (lane < 32) ev = hbuf[w][lane]*wEv[lane];
  } else {
    if (lane < 16){
      float hid = 0.f;
      #pragma unroll
      for (int c = 0; c < 32; c++) hid = fmaf(hbuf[w][c], Whg[c*16+lane], hid);
      hid = silu_f(hid);
      ev = hid * wE2g[lane];
    }
  }
  #pragma unroll
  for (int off = 16; off >= 1; off >>= 1){
    ev  += __shfl_down(ev,  off);
    dv0 += __shfl_down(dv0, off);
    dv1 += __shfl_down(dv1, off);
    dv2 += __shfl_down(dv2, off);
  }
  if (lane == 0){
    atomicAdd(&glds[g][0], ev);
    atomicAdd(&glds[g][1], dv0);
    atomicAdd(&glds[g][2], dv1);
    atomicAdd(&glds[g][3], dv2);
  }
  __syncthreads();
  if (tid < NG*4){
    float v = glds[tid>>2][tid&3];
    if (v != 0.f) atomicAdd(out + tid, v);
  }
}

// ---------------------------------------------------------------- launch
extern "C" void kernel_launch(void* const* d_in, const int* in_sizes, int n_in,
                              void* d_out, int out_size, void* d_ws, size_t ws_size,
                              hipStream_t stream){
  const float* positions       = (const float*)d_in[0];
  const float* node_attrs      = (const float*)d_in[1];
  const float* charges         = (const float*)d_in[2];
  const float* atomic_energies = (const float*)d_in[3];
  const float* W_embed         = (const float*)d_in[4];
  const float* R0              = (const float*)d_in[5];
  const float* R1              = (const float*)d_in[6];
  const float* R2              = (const float*)d_in[7];
  const float* R3              = (const float*)d_in[8];
  const float* W_mix           = (const float*)d_in[9];
  const float* W_sc            = (const float*)d_in[10];
  const float* Wp1             = (const float*)d_in[11];
  const float* Wp2             = (const float*)d_in[12];
  const float* Wp3             = (const float*)d_in[13];
  const float* wE1             = (const float*)d_in[14];
  const float* wD1             = (const float*)d_in[15];
  const float* Wh              = (const float*)d_in[16];
  const float* wE2             = (const float*)d_in[17];
  const float* wD2             = (const float*)d_in[18];
  const int*   edge_index      = (const int*)d_in[19];
  const int*   batch           = (const int*)d_in[20];
  float* out = (float*)d_out;

  char* wsp = (char*)d_ws;
  float* P   = (float*)wsp; wsp += sizeof(float)*(size_t)N_EDGES*96;
  float* Ye  = (float*)wsp; wsp += sizeof(float)*(size_t)N_EDGES*16;
  float* RBt = (float*)wsp; wsp += sizeof(float)*(size_t)NB*N_EDGES;
  float* hg  = (float*)wsp; wsp += sizeof(float)*(size_t)N_NODES*288;
  int* counts    = (int*)wsp; wsp += sizeof(int)*N_NODES;
  int* row_start = (int*)wsp; wsp += sizeof(int)*(N_NODES+64);
  int* cursor    = (int*)wsp; wsp += sizeof(int)*N_NODES;
  int* order     = (int*)wsp; wsp += sizeof(int)*N_EDGES;
  int* snd_perm  = (int*)wsp; wsp += sizeof(int)*N_EDGES;
  int* species   = (int*)wsp; wsp += sizeof(int)*N_NODES;

  hipMemsetAsync(d_out, 0, 64*sizeof(float), stream);
  hipMemsetAsync(counts, 0, N_NODES*sizeof(int), stream);
  hipMemsetAsync(hg, 0, sizeof(float)*(size_t)N_NODES*288, stream);

  hist_kernel<<<N_EDGES/256, 256, 0, stream>>>(edge_index, counts);
  scan_kernel<<<1, 256, 0, stream>>>(counts, row_start, cursor);
  fill_kernel<<<N_EDGES/256, 256, 0, stream>>>(edge_index, cursor, order);
  spec_kernel<<<N_NODES/256, 256, 0, stream>>>(node_attrs, atomic_energies, charges,
                                               positions, batch, species, out);
  h0_kernel<<<N_NODES*32/256, 256, 0, stream>>>(species, W_embed, hg);
  geom_kernel<<<N_EDGES/128, 128, 0, stream>>>(positions, edge_index, order,
                                               snd_perm, Ye, RBt);

  for (int i = 0; i < 2; i++){
    edge_kernel<<<N_EDGES/128, 128, 0, stream>>>(R0 + i*NB*H, R1 + i*H*H, R2 + i*H*H,
                                                 R3 + i*H*96, RBt, hg, snd_perm, P);
    node_kernel<<<N_NODES/4, 256, 0, stream>>>(P, Ye, row_start, hg,
                                               W_mix + i*3*C*C, W_sc + i*3*C*C,
                                               Wp1 + i*Zn*C, Wp2 + i*Zn*C, Wp3 + i*Zn*C,
                                               species, batch,
                                               wE1, (i == 0) ? wD1 : wD2,
                                               Wh, wE2, i, out);
  }
}

// Round 5
// 418.183 us; speedup vs baseline: 1.2717x; 1.2717x over previous
//
#include <hip/hip_runtime.h>
#include <math.h>

#define N_NODES 8192
#define N_EDGES 131072
#define C 32
#define Zn 10
#define NG 16
#define NSH 9
#define NB 8
#define H 64
#define TABN 8192
#define PPB 16     // table points per block
#define XS 73      // activation LDS stride (bank-scatter pad)

__device__ __forceinline__ float silu_f(float v){ return v / (1.0f + __expf(-v)); }

// ---------------------------------------------------------------- CSR build
__global__ __launch_bounds__(256)
void hist_kernel(const int* __restrict__ ei, int* __restrict__ counts){
  int e = blockIdx.x*256 + threadIdx.x;
  atomicAdd(counts + ei[N_EDGES + e], 1);
}

__global__ __launch_bounds__(256)
void scan_kernel(const int* __restrict__ counts, int* __restrict__ row_start,
                 int* __restrict__ cursor){
  __shared__ int part[256];
  int tid = threadIdx.x;
  int base = tid*32;
  int local[32];
  int s = 0;
  #pragma unroll
  for (int i = 0; i < 32; i++){ local[i] = s; s += counts[base+i]; }
  part[tid] = s; __syncthreads();
  for (int off = 1; off < 256; off <<= 1){
    int v = (tid >= off) ? part[tid-off] : 0;
    __syncthreads();
    part[tid] += v;
    __syncthreads();
  }
  int excl = part[tid] - s;
  #pragma unroll
  for (int i = 0; i < 32; i++){
    int v = excl + local[i];
    row_start[base+i] = v;
    cursor[base+i] = v;
  }
  if (tid == 255) row_start[N_NODES] = part[255];
}

__global__ __launch_bounds__(256)
void fill_kernel(const int* __restrict__ ei, int* __restrict__ cursor,
                 int* __restrict__ order){
  int e = blockIdx.x*256 + threadIdx.x;
  int rcv = ei[N_EDGES + e];
  int pos = atomicAdd(cursor + rcv, 1);
  order[pos] = e;
}

// ---------------------------------------------------------------- species + baseline outputs
__global__ __launch_bounds__(256)
void spec_kernel(const float* __restrict__ na, const float* __restrict__ ae,
                 const float* __restrict__ charges, const float* __restrict__ pos,
                 const int* __restrict__ batch, int* __restrict__ species,
                 float* __restrict__ out){
  __shared__ float glds[NG][4];
  int tid = threadIdx.x;
  if (tid < NG*4) glds[tid>>2][tid&3] = 0.f;
  __syncthreads();
  int n = blockIdx.x*256 + tid;
  int spec = 0;
  #pragma unroll
  for (int z = 1; z < Zn; z++) if (na[n*Zn+z] > 0.5f) spec = z;
  species[n] = spec;
  int g = batch[n];
  float q = charges[n];
  atomicAdd(&glds[g][0], ae[spec]);
  atomicAdd(&glds[g][1], q*pos[n*3+0]);
  atomicAdd(&glds[g][2], q*pos[n*3+1]);
  atomicAdd(&glds[g][3], q*pos[n*3+2]);
  __syncthreads();
  if (tid < NG*4){
    float v = glds[tid>>2][tid&3];
    if (v != 0.f) atomicAdd(out + tid, v);
  }
}

__global__ __launch_bounds__(256)
void h0_kernel(const int* __restrict__ species, const float* __restrict__ Wemb,
               float* __restrict__ hg){
  int idx = blockIdx.x*256 + threadIdx.x;        // [0, N*32)
  int n = idx >> 5, c = idx & 31;
  hg[(size_t)n*288 + c] = Wemb[species[n]*C + c];
}

// ---------------------------------------------------------------- geometry (CSR-slot order)
__global__ __launch_bounds__(128)
void geom_kernel(const float* __restrict__ pos, const int* __restrict__ ei,
                 const int* __restrict__ order, int* __restrict__ snd_perm,
                 float* __restrict__ Ye, float* __restrict__ r_perm){
  int t = blockIdx.x*128 + threadIdx.x;          // CSR slot
  int e = order[t];
  int snd = ei[e], rcv = ei[N_EDGES + e];
  snd_perm[t] = snd;
  float px = pos[rcv*3+0]-pos[snd*3+0];
  float py = pos[rcv*3+1]-pos[snd*3+1];
  float pz = pos[rcv*3+2]-pos[snd*3+2];
  float r2 = px*px+py*py+pz*pz + 1e-12f;
  float r = sqrtf(r2);
  r_perm[t] = r;
  float inv = 1.0f/r;
  float x = px*inv, y = py*inv, z = pz*inv;
  const float s3 = 1.7320508075688772f;
  const float s5 = 2.23606797749979f;
  const float s15 = 3.872983346207417f;
  float* ye = Ye + (size_t)t*16;
  ye[0] = 1.0f;
  ye[1] = s3*x;
  ye[2] = s3*y;
  ye[3] = s3*z;
  ye[4] = s15*x*y;
  ye[5] = s15*y*z;
  ye[6] = 0.5f*s5*(3.0f*z*z-1.0f);
  ye[7] = s15*x*z;
  ye[8] = 0.5f*s15*(x*x-y*y);
}

// ---------------------------------------------------------------- radial MLP table
// Tab[i][96] = MLP(rb(r_i)), r_i = i*R_MAX/TABN.  8 threads per point (j-split).
__global__ __launch_bounds__(128)
void table_kernel(const float* __restrict__ R0i, const float* __restrict__ R1i,
                  const float* __restrict__ R2i, const float* __restrict__ R3i,
                  float* __restrict__ Tab){
  __shared__ float xsh[PPB*XS];
  int tid = threadIdx.x;
  int pl = tid >> 3, jt = tid & 7;
  int i = blockIdx.x*PPB + pl;
  float r = (i == 0) ? 1e-6f : (float)i * (5.0f/TABN);
  // rb feature k = jt
  {
    float xr = r*0.2f;
    float env = 0.f;
    if (xr < 1.0f){
      float x2 = xr*xr, x5 = x2*x2*xr;
      env = 1.f - 21.f*x5 + 35.f*x5*xr - 15.f*x5*x2;
    }
    float sc = 0.6324555320336759f / r * env;
    xsh[pl*XS + jt] = sc * sinf((float)(jt+1)*0.6283185307179586f*r);
  }
  __syncthreads();

  float acc[12];
  // layer 0: 8 -> 64
  #pragma unroll
  for (int j = 0; j < 8; j++) acc[j] = 0.f;
  #pragma unroll
  for (int k = 0; k < 8; k++){
    float xk = xsh[pl*XS + k];
    const float4* w4 = (const float4*)(R0i + k*H + jt*8);
    float4 wa = w4[0], wb = w4[1];
    acc[0]=fmaf(xk,wa.x,acc[0]); acc[1]=fmaf(xk,wa.y,acc[1]);
    acc[2]=fmaf(xk,wa.z,acc[2]); acc[3]=fmaf(xk,wa.w,acc[3]);
    acc[4]=fmaf(xk,wb.x,acc[4]); acc[5]=fmaf(xk,wb.y,acc[5]);
    acc[6]=fmaf(xk,wb.z,acc[6]); acc[7]=fmaf(xk,wb.w,acc[7]);
  }
  __syncthreads();
  #pragma unroll
  for (int j = 0; j < 8; j++) xsh[pl*XS + jt*8 + j] = silu_f(acc[j]);
  __syncthreads();

  // layers 1, 2: 64 -> 64
  const float* Wl[2] = {R1i, R2i};
  #pragma unroll
  for (int L = 0; L < 2; L++){
    const float* W = Wl[L];
    #pragma unroll
    for (int j = 0; j < 8; j++) acc[j] = 0.f;
    for (int k = 0; k < H; k++){
      float xk = xsh[pl*XS + k];
      const float4* w4 = (const float4*)(W + k*H + jt*8);
      float4 wa = w4[0], wb = w4[1];
      acc[0]=fmaf(xk,wa.x,acc[0]); acc[1]=fmaf(xk,wa.y,acc[1]);
      acc[2]=fmaf(xk,wa.z,acc[2]); acc[3]=fmaf(xk,wa.w,acc[3]);
      acc[4]=fmaf(xk,wb.x,acc[4]); acc[5]=fmaf(xk,wb.y,acc[5]);
      acc[6]=fmaf(xk,wb.z,acc[6]); acc[7]=fmaf(xk,wb.w,acc[7]);
    }
    __syncthreads();
    #pragma unroll
    for (int j = 0; j < 8; j++) xsh[pl*XS + jt*8 + j] = silu_f(acc[j]);
    __syncthreads();
  }

  // layer 3: 64 -> 96, 12 outputs per thread, no silu
  #pragma unroll
  for (int j = 0; j < 12; j++) acc[j] = 0.f;
  for (int k = 0; k < H; k++){
    float xk = xsh[pl*XS + k];
    const float4* w4 = (const float4*)(R3i + k*96 + jt*12);
    float4 wa = w4[0], wb = w4[1], wc = w4[2];
    acc[0]=fmaf(xk,wa.x,acc[0]);  acc[1]=fmaf(xk,wa.y,acc[1]);
    acc[2]=fmaf(xk,wa.z,acc[2]);  acc[3]=fmaf(xk,wa.w,acc[3]);
    acc[4]=fmaf(xk,wb.x,acc[4]);  acc[5]=fmaf(xk,wb.y,acc[5]);
    acc[6]=fmaf(xk,wb.z,acc[6]);  acc[7]=fmaf(xk,wb.w,acc[7]);
    acc[8]=fmaf(xk,wc.x,acc[8]);  acc[9]=fmaf(xk,wc.y,acc[9]);
    acc[10]=fmaf(xk,wc.z,acc[10]); acc[11]=fmaf(xk,wc.w,acc[11]);
  }
  if (i <= TABN){
    float* trow = Tab + (size_t)i*96 + jt*12;
    #pragma unroll
    for (int j = 0; j < 12; j += 4)
      *(float4*)(trow + j) = make_float4(acc[j],acc[j+1],acc[j+2],acc[j+3]);
  }
}

// ---------------------------------------------------------------- apply: P[t][96] = lerp(Tab, r_t) * h_snd
__global__ __launch_bounds__(256)
void apply_kernel(const float* __restrict__ Tab, const float* __restrict__ r_perm,
                  const int* __restrict__ snd_perm, const float* __restrict__ hg,
                  float* __restrict__ P){
  int t = blockIdx.x*256 + threadIdx.x;
  float r = r_perm[t];
  int snd = snd_perm[t];
  float4 hs4[8];
  const float4* hrow = (const float4*)(hg + (size_t)snd*288);
  #pragma unroll
  for (int q = 0; q < 8; q++) hs4[q] = hrow[q];
  float4* Prow = (float4*)(P + (size_t)t*96);
  if (r < 5.0f){
    float u = r * (TABN/5.0f);
    int i0 = (int)u;
    if (i0 > TABN-1) i0 = TABN-1;
    float f = u - (float)i0;
    const float4* T0 = (const float4*)(Tab + (size_t)i0*96);
    const float4* T1 = T0 + 24;
    #pragma unroll
    for (int q = 0; q < 24; q++){
      float4 a = T0[q], b = T1[q];
      float4 h = hs4[q & 7];
      float4 v;
      v.x = fmaf(b.x - a.x, f, a.x) * h.x;
      v.y = fmaf(b.y - a.y, f, a.y) * h.y;
      v.z = fmaf(b.z - a.z, f, a.z) * h.z;
      v.w = fmaf(b.w - a.w, f, a.w) * h.w;
      Prow[q] = v;
    }
  } else {
    float4 z = make_float4(0.f,0.f,0.f,0.f);
    #pragma unroll
    for (int q = 0; q < 24; q++) Prow[q] = z;
  }
}

// ---------------------------------------------------------------- node: contiguous gather + mix + gate + readout
__global__ __launch_bounds__(256)
void node_kernel(const float* __restrict__ P, const float* __restrict__ Ye,
                 const int* __restrict__ row_start,
                 float* __restrict__ hg,
                 const float* __restrict__ Wm_g, const float* __restrict__ Ws_g,
                 const float* __restrict__ Wp1, const float* __restrict__ Wp2,
                 const float* __restrict__ Wp3,
                 const int* __restrict__ species, const int* __restrict__ batch,
                 const float* __restrict__ wEv, const float* __restrict__ wDv,
                 const float* __restrict__ Whg, const float* __restrict__ wE2g,
                 int iter, float* __restrict__ out){
  __shared__ float Wm[3*32*32];
  __shared__ float Ws[3*32*32];
  __shared__ float abuf[4][288];
  __shared__ float hbuf[4][288];
  __shared__ float glds[NG][4];
  int tid = threadIdx.x;
  for (int t = tid; t < 3072; t += 256){ Wm[t] = Wm_g[t]; Ws[t] = Ws_g[t]; }
  if (tid < NG*4) glds[tid>>2][tid&3] = 0.f;
  int w = tid >> 6, lane = tid & 63;
  int n = blockIdx.x*4 + w;
  for (int idx = lane; idx < 288; idx += 64){
    hbuf[w][idx] = hg[(long)n*288+idx];
  }

  // ---- gather A[m][c] = sum_{slots j of n} P[j][lmap[m]*32+c] * Ye[j][m]
  int cols[5], ms[5]; bool act5[5];
  #pragma unroll
  for (int s = 0; s < 5; s++){
    int idx = lane + s*64;
    act5[s] = (idx < 288);
    int m = act5[s] ? (idx >> 5) : 0;
    int l = (m >= 4) ? 2 : ((m >= 1) ? 1 : 0);
    cols[s] = l*32 + (idx & 31);
    ms[s] = m;
  }
  float acc[5] = {0.f,0.f,0.f,0.f,0.f};
  int jb = row_start[n], je = row_start[n+1];
  const float* Pe = P + (size_t)jb*96;
  const float* Yv = Ye + (size_t)jb*16;
  #pragma unroll 2
  for (int j = jb; j < je; j++){
    #pragma unroll
    for (int s = 0; s < 5; s++){
      if (act5[s]) acc[s] = fmaf(Pe[cols[s]], Yv[ms[s]], acc[s]);
    }
    Pe += 96; Yv += 16;
  }
  #pragma unroll
  for (int s = 0; s < 5; s++){
    int idx = lane + s*64;
    if (act5[s]) abuf[w][idx] = acc[s] * (1.0f/16.0f);
  }
  __syncthreads();

  // ---- mix: A @ W_mix[lmap], sc = h @ W_sc[lmap]
  float amv[5], scv[5];
  #pragma unroll
  for (int it = 0; it < 5; it++){
    int idx = it*64 + lane;
    amv[it] = 0.f; scv[it] = 0.f;
    if (idx < 288){
      int m = idx >> 5, d = idx & 31;
      int l = (m >= 4) ? 2 : ((m >= 1) ? 1 : 0);
      const float* wm = Wm + l*1024 + d;
      const float* ws = Ws + l*1024 + d;
      float a2 = 0.f, sc = 0.f;
      #pragma unroll
      for (int c = 0; c < 32; c++){
        a2 = fmaf(abuf[w][m*32+c], wm[c*32], a2);
        sc = fmaf(hbuf[w][m*32+c], ws[c*32], sc);
      }
      amv[it] = a2; scv[it] = sc;
    }
  }
  __syncthreads();
  #pragma unroll
  for (int it = 0; it < 5; it++){ int idx = it*64+lane; if (idx < 288) abuf[w][idx] = amv[it]; }
  __syncthreads();

  int d = lane & 31;
  float sval = abuf[w][d];
  int spec = species[n];
  float p1 = Wp1[spec*C+d], p2 = Wp2[spec*C+d], p3 = Wp3[spec*C+d];
  float f = p1 + p2*sval + p3*sval*sval;
  #pragma unroll
  for (int it = 0; it < 5; it++){
    int idx = it*64 + lane;
    if (idx < 288){
      float hn = amv[it]*f + scv[it];
      hg[(long)n*288+idx] = hn;
      hbuf[w][idx] = hn;
    }
  }
  __syncthreads();

  int g = batch[n];
  float dv0 = 0.f, dv1 = 0.f, dv2 = 0.f, ev = 0.f;
  if (lane < 32){
    dv0 = hbuf[w][32+lane]*wDv[lane];
    dv1 = hbuf[w][64+lane]*wDv[lane];
    dv2 = hbuf[w][96+lane]*wDv[lane];
  }
  if (iter == 0){
    if (lane < 32) ev = hbuf[w][lane]*wEv[lane];
  } else {
    if (lane < 16){
      float hid = 0.f;
      #pragma unroll
      for (int c = 0; c < 32; c++) hid = fmaf(hbuf[w][c], Whg[c*16+lane], hid);
      hid = silu_f(hid);
      ev = hid * wE2g[lane];
    }
  }
  #pragma unroll
  for (int off = 16; off >= 1; off >>= 1){
    ev  += __shfl_down(ev,  off);
    dv0 += __shfl_down(dv0, off);
    dv1 += __shfl_down(dv1, off);
    dv2 += __shfl_down(dv2, off);
  }
  if (lane == 0){
    atomicAdd(&glds[g][0], ev);
    atomicAdd(&glds[g][1], dv0);
    atomicAdd(&glds[g][2], dv1);
    atomicAdd(&glds[g][3], dv2);
  }
  __syncthreads();
  if (tid < NG*4){
    float v = glds[tid>>2][tid&3];
    if (v != 0.f) atomicAdd(out + tid, v);
  }
}

// ---------------------------------------------------------------- launch
extern "C" void kernel_launch(void* const* d_in, const int* in_sizes, int n_in,
                              void* d_out, int out_size, void* d_ws, size_t ws_size,
                              hipStream_t stream){
  const float* positions       = (const float*)d_in[0];
  const float* node_attrs      = (const float*)d_in[1];
  const float* charges         = (const float*)d_in[2];
  const float* atomic_energies = (const float*)d_in[3];
  const float* W_embed         = (const float*)d_in[4];
  const float* R0              = (const float*)d_in[5];
  const float* R1              = (const float*)d_in[6];
  const float* R2              = (const float*)d_in[7];
  const float* R3              = (const float*)d_in[8];
  const float* W_mix           = (const float*)d_in[9];
  const float* W_sc            = (const float*)d_in[10];
  const float* Wp1             = (const float*)d_in[11];
  const float* Wp2             = (const float*)d_in[12];
  const float* Wp3             = (const float*)d_in[13];
  const float* wE1             = (const float*)d_in[14];
  const float* wD1             = (const float*)d_in[15];
  const float* Wh              = (const float*)d_in[16];
  const float* wE2             = (const float*)d_in[17];
  const float* wD2             = (const float*)d_in[18];
  const int*   edge_index      = (const int*)d_in[19];
  const int*   batch           = (const int*)d_in[20];
  float* out = (float*)d_out;

  char* wsp = (char*)d_ws;
  float* P    = (float*)wsp; wsp += sizeof(float)*(size_t)N_EDGES*96;
  float* Ye   = (float*)wsp; wsp += sizeof(float)*(size_t)N_EDGES*16;
  float* Tab  = (float*)wsp; wsp += sizeof(float)*(size_t)(TABN+1)*96;
  float* hg   = (float*)wsp; wsp += sizeof(float)*(size_t)N_NODES*288;
  float* r_perm = (float*)wsp; wsp += sizeof(float)*N_EDGES;
  int* counts    = (int*)wsp; wsp += sizeof(int)*N_NODES;
  int* row_start = (int*)wsp; wsp += sizeof(int)*(N_NODES+64);
  int* cursor    = (int*)wsp; wsp += sizeof(int)*N_NODES;
  int* order     = (int*)wsp; wsp += sizeof(int)*N_EDGES;
  int* snd_perm  = (int*)wsp; wsp += sizeof(int)*N_EDGES;
  int* species   = (int*)wsp; wsp += sizeof(int)*N_NODES;

  hipMemsetAsync(d_out, 0, 64*sizeof(float), stream);
  hipMemsetAsync(counts, 0, N_NODES*sizeof(int), stream);
  hipMemsetAsync(hg, 0, sizeof(float)*(size_t)N_NODES*288, stream);

  hist_kernel<<<N_EDGES/256, 256, 0, stream>>>(edge_index, counts);
  scan_kernel<<<1, 256, 0, stream>>>(counts, row_start, cursor);
  fill_kernel<<<N_EDGES/256, 256, 0, stream>>>(edge_index, cursor, order);
  spec_kernel<<<N_NODES/256, 256, 0, stream>>>(node_attrs, atomic_energies, charges,
                                               positions, batch, species, out);
  h0_kernel<<<N_NODES*32/256, 256, 0, stream>>>(species, W_embed, hg);
  geom_kernel<<<N_EDGES/128, 128, 0, stream>>>(positions, edge_index, order,
                                               snd_perm, Ye, r_perm);

  for (int i = 0; i < 2; i++){
    table_kernel<<<(TABN+PPB)/PPB, 128, 0, stream>>>(R0 + i*NB*H, R1 + i*H*H,
                                                     R2 + i*H*H, R3 + i*H*96, Tab);
    apply_kernel<<<N_EDGES/256, 256, 0, stream>>>(Tab, r_perm, snd_perm, hg, P);
    node_kernel<<<N_NODES/4, 256, 0, stream>>>(P, Ye, row_start, hg,
                                               W_mix + i*3*C*C, W_sc + i*3*C*C,
                                               Wp1 + i*Zn*C, Wp2 + i*Zn*C, Wp3 + i*Zn*C,
                                               species, batch,
                                               wE1, (i == 0) ? wD1 : wD2,
                                               Wh, wE2, i, out);
  }
}

// Round 6
// 308.897 us; speedup vs baseline: 1.7217x; 1.3538x over previous
//
#include <hip/hip_runtime.h>
#include <math.h>

#define N_NODES 8192
#define N_EDGES 131072
#define C 32
#define Zn 10
#define NG 16
#define NB 8
#define H 64
#define TABN 4096
#define PPB 16     // table points per block
#define XS 73      // table kernel activation LDS stride
#define TAB_STRIDE ((TABN+1)*96)

__device__ __forceinline__ float silu_f(float v){ return v / (1.0f + __expf(-v)); }

// ---------------------------------------------------------------- r + histogram (cutoff-filtered)
__global__ __launch_bounds__(256)
void hist_geom_kernel(const float* __restrict__ pos, const int* __restrict__ ei,
                      int* __restrict__ counts, float4* __restrict__ xyzr){
  int e = blockIdx.x*256 + threadIdx.x;
  int snd = ei[e], rcv = ei[N_EDGES + e];
  float px = pos[rcv*3+0]-pos[snd*3+0];
  float py = pos[rcv*3+1]-pos[snd*3+1];
  float pz = pos[rcv*3+2]-pos[snd*3+2];
  float r = sqrtf(px*px+py*py+pz*pz + 1e-12f);
  float inv = 1.0f/r;
  xyzr[e] = make_float4(px*inv, py*inv, pz*inv, r);
  if (r < 5.0f) atomicAdd(counts + rcv, 1);
}

__global__ __launch_bounds__(256)
void scan_kernel(const int* __restrict__ counts, int* __restrict__ row_start,
                 int* __restrict__ cursor){
  __shared__ int part[256];
  int tid = threadIdx.x;
  int base = tid*32;
  int local[32];
  int s = 0;
  #pragma unroll
  for (int i = 0; i < 32; i++){ local[i] = s; s += counts[base+i]; }
  part[tid] = s; __syncthreads();
  for (int off = 1; off < 256; off <<= 1){
    int v = (tid >= off) ? part[tid-off] : 0;
    __syncthreads();
    part[tid] += v;
    __syncthreads();
  }
  int excl = part[tid] - s;
  #pragma unroll
  for (int i = 0; i < 32; i++){
    int v = excl + local[i];
    row_start[base+i] = v;
    cursor[base+i] = v;
  }
  if (tid == 255) row_start[N_NODES] = part[255];
}

// ---------------------------------------------------------------- fill CSR slots + inline Y
__global__ __launch_bounds__(256)
void fill_geom_kernel(const float4* __restrict__ xyzr, const int* __restrict__ ei,
                      int* __restrict__ cursor, float* __restrict__ Ye,
                      float* __restrict__ r_perm, int* __restrict__ snd_perm){
  int e = blockIdx.x*256 + threadIdx.x;
  float4 v = xyzr[e];
  if (v.w < 5.0f){
    int rcv = ei[N_EDGES + e];
    int p = atomicAdd(cursor + rcv, 1);
    float x = v.x, y = v.y, z = v.z;
    const float s3 = 1.7320508075688772f;
    const float s5 = 2.23606797749979f;
    const float s15 = 3.872983346207417f;
    float* ye = Ye + (size_t)p*16;
    *(float4*)(ye)   = make_float4(1.f, s3*x, s3*y, s3*z);
    *(float4*)(ye+4) = make_float4(s15*x*y, s15*y*z, 0.5f*s5*(3.f*z*z-1.f), s15*x*z);
    ye[8] = 0.5f*s15*(x*x-y*y);
    r_perm[p] = v.w;
    snd_perm[p] = ei[e];
  }
}

// ---------------------------------------------------------------- species + baseline outputs
__global__ __launch_bounds__(256)
void spec_kernel(const float* __restrict__ na, const float* __restrict__ ae,
                 const float* __restrict__ charges, const float* __restrict__ pos,
                 const int* __restrict__ batch, int* __restrict__ species,
                 float* __restrict__ out){
  __shared__ float glds[NG][4];
  int tid = threadIdx.x;
  if (tid < NG*4) glds[tid>>2][tid&3] = 0.f;
  __syncthreads();
  int n = blockIdx.x*256 + tid;
  int spec = 0;
  #pragma unroll
  for (int z = 1; z < Zn; z++) if (na[n*Zn+z] > 0.5f) spec = z;
  species[n] = spec;
  int g = batch[n];
  float q = charges[n];
  atomicAdd(&glds[g][0], ae[spec]);
  atomicAdd(&glds[g][1], q*pos[n*3+0]);
  atomicAdd(&glds[g][2], q*pos[n*3+1]);
  atomicAdd(&glds[g][3], q*pos[n*3+2]);
  __syncthreads();
  if (tid < NG*4){
    float v = glds[tid>>2][tid&3];
    if (v != 0.f) atomicAdd(out + tid, v);
  }
}

__global__ __launch_bounds__(256)
void h0_kernel(const int* __restrict__ species, const float* __restrict__ Wemb,
               float* __restrict__ hg){
  int idx = blockIdx.x*256 + threadIdx.x;        // [0, N*32)
  int n = idx >> 5, c = idx & 31;
  hg[(size_t)n*288 + c] = Wemb[species[n]*C + c];
}

// ---------------------------------------------------------------- radial MLP tables (both iterations)
__global__ __launch_bounds__(128)
void table_kernel(const float* __restrict__ R0g, const float* __restrict__ R1g,
                  const float* __restrict__ R2g, const float* __restrict__ R3g,
                  float* __restrict__ Tab){
  __shared__ float xsh[PPB*XS];
  const int nb = (TABN + PPB) / PPB;   // 257
  int half = blockIdx.x / nb;
  int blk  = blockIdx.x - half*nb;
  const float* R0i = R0g + half*NB*H;
  const float* R1i = R1g + half*H*H;
  const float* R2i = R2g + half*H*H;
  const float* R3i = R3g + half*H*96;
  float* TabH = Tab + (size_t)half*TAB_STRIDE;

  int tid = threadIdx.x;
  int pl = tid >> 3, jt = tid & 7;
  int i = blk*PPB + pl;
  float r = (i == 0) ? 1e-6f : (float)i * (5.0f/TABN);
  {
    float xr = r*0.2f;
    float env = 0.f;
    if (xr < 1.0f){
      float x2 = xr*xr, x5 = x2*x2*xr;
      env = 1.f - 21.f*x5 + 35.f*x5*xr - 15.f*x5*x2;
    }
    float sc = 0.6324555320336759f / r * env;
    xsh[pl*XS + jt] = sc * sinf((float)(jt+1)*0.6283185307179586f*r);
  }
  __syncthreads();

  float acc[12];
  #pragma unroll
  for (int j = 0; j < 8; j++) acc[j] = 0.f;
  #pragma unroll
  for (int k = 0; k < 8; k++){
    float xk = xsh[pl*XS + k];
    const float4* w4 = (const float4*)(R0i + k*H + jt*8);
    float4 wa = w4[0], wb = w4[1];
    acc[0]=fmaf(xk,wa.x,acc[0]); acc[1]=fmaf(xk,wa.y,acc[1]);
    acc[2]=fmaf(xk,wa.z,acc[2]); acc[3]=fmaf(xk,wa.w,acc[3]);
    acc[4]=fmaf(xk,wb.x,acc[4]); acc[5]=fmaf(xk,wb.y,acc[5]);
    acc[6]=fmaf(xk,wb.z,acc[6]); acc[7]=fmaf(xk,wb.w,acc[7]);
  }
  __syncthreads();
  #pragma unroll
  for (int j = 0; j < 8; j++) xsh[pl*XS + jt*8 + j] = silu_f(acc[j]);
  __syncthreads();

  const float* Wl[2] = {R1i, R2i};
  #pragma unroll
  for (int L = 0; L < 2; L++){
    const float* W = Wl[L];
    #pragma unroll
    for (int j = 0; j < 8; j++) acc[j] = 0.f;
    for (int k = 0; k < H; k++){
      float xk = xsh[pl*XS + k];
      const float4* w4 = (const float4*)(W + k*H + jt*8);
      float4 wa = w4[0], wb = w4[1];
      acc[0]=fmaf(xk,wa.x,acc[0]); acc[1]=fmaf(xk,wa.y,acc[1]);
      acc[2]=fmaf(xk,wa.z,acc[2]); acc[3]=fmaf(xk,wa.w,acc[3]);
      acc[4]=fmaf(xk,wb.x,acc[4]); acc[5]=fmaf(xk,wb.y,acc[5]);
      acc[6]=fmaf(xk,wb.z,acc[6]); acc[7]=fmaf(xk,wb.w,acc[7]);
    }
    __syncthreads();
    #pragma unroll
    for (int j = 0; j < 8; j++) xsh[pl*XS + jt*8 + j] = silu_f(acc[j]);
    __syncthreads();
  }

  #pragma unroll
  for (int j = 0; j < 12; j++) acc[j] = 0.f;
  for (int k = 0; k < H; k++){
    float xk = xsh[pl*XS + k];
    const float4* w4 = (const float4*)(R3i + k*96 + jt*12);
    float4 wa = w4[0], wb = w4[1], wc = w4[2];
    acc[0]=fmaf(xk,wa.x,acc[0]);  acc[1]=fmaf(xk,wa.y,acc[1]);
    acc[2]=fmaf(xk,wa.z,acc[2]);  acc[3]=fmaf(xk,wa.w,acc[3]);
    acc[4]=fmaf(xk,wb.x,acc[4]);  acc[5]=fmaf(xk,wb.y,acc[5]);
    acc[6]=fmaf(xk,wb.z,acc[6]);  acc[7]=fmaf(xk,wb.w,acc[7]);
    acc[8]=fmaf(xk,wc.x,acc[8]);  acc[9]=fmaf(xk,wc.y,acc[9]);
    acc[10]=fmaf(xk,wc.z,acc[10]); acc[11]=fmaf(xk,wc.w,acc[11]);
  }
  if (i <= TABN){
    float* trow = TabH + (size_t)i*96 + jt*12;
    #pragma unroll
    for (int j = 0; j < 12; j += 4)
      *(float4*)(trow + j) = make_float4(acc[j],acc[j+1],acc[j+2],acc[j+3]);
  }
}

// ---------------------------------------------------------------- node: fused table-lerp gather + mix + gate + readout
__global__ __launch_bounds__(256)
void node_kernel(const float* __restrict__ Tab, const float* __restrict__ Ye,
                 const float* __restrict__ r_perm, const int* __restrict__ snd_perm,
                 const int* __restrict__ row_start,
                 const float* __restrict__ hg_in, float* __restrict__ hg_out,
                 const float* __restrict__ Wm_g, const float* __restrict__ Ws_g,
                 const float* __restrict__ Wp1, const float* __restrict__ Wp2,
                 const float* __restrict__ Wp3,
                 const int* __restrict__ species, const int* __restrict__ batch,
                 const float* __restrict__ wEv, const float* __restrict__ wDv,
                 const float* __restrict__ Whg, const float* __restrict__ wE2g,
                 int iter, float* __restrict__ out){
  __shared__ float Wm[3*32*32];
  __shared__ float Ws[3*32*32];
  __shared__ float abuf[4][288];
  __shared__ float hbuf[4][288];
  __shared__ float glds[NG][4];
  int tid = threadIdx.x;
  for (int t = tid; t < 3072; t += 256){ Wm[t] = Wm_g[t]; Ws[t] = Ws_g[t]; }
  if (tid < NG*4) glds[tid>>2][tid&3] = 0.f;
  int w = tid >> 6, lane = tid & 63;
  int c31 = lane & 31;
  int n = blockIdx.x*4 + w;
  for (int idx = lane; idx < 288; idx += 64){
    hbuf[w][idx] = hg_in[(size_t)n*288+idx];
  }

  // ---- gather A[m][c] = sum_{active edges j of n} lerp(Tab,r_j)[col] * hs_j[c] * Ye[j][m]
  int cols[5], ms[5]; bool act5[5];
  #pragma unroll
  for (int s = 0; s < 5; s++){
    int idx = lane + s*64;
    act5[s] = (idx < 288);
    int m = act5[s] ? (idx >> 5) : 0;
    int l = (m >= 4) ? 2 : ((m >= 1) ? 1 : 0);
    cols[s] = l*32 + (idx & 31);
    ms[s] = m;
  }
  float acc[5] = {0.f,0.f,0.f,0.f,0.f};
  int jb = row_start[n], je = row_start[n+1];
  #pragma unroll 2
  for (int j = jb; j < je; j++){
    float r  = r_perm[j];                      // wave-uniform
    int snd  = snd_perm[j];                    // wave-uniform
    float u  = r * (TABN/5.0f);
    int i0   = (int)u;
    if (i0 > TABN-1) i0 = TABN-1;
    float f  = u - (float)i0;
    const float* T0 = Tab + (size_t)i0*96;
    float hs = hg_in[(size_t)snd*288 + c31];   // 128B broadcast row
    const float* Yv = Ye + (size_t)j*16;
    #pragma unroll
    for (int s = 0; s < 5; s++){
      if (act5[s]){
        float a = T0[cols[s]];
        float b = T0[cols[s]+96];
        float wv = fmaf(b - a, f, a);
        acc[s] = fmaf(wv*hs, Yv[ms[s]], acc[s]);
      }
    }
  }
  #pragma unroll
  for (int s = 0; s < 5; s++){
    int idx = lane + s*64;
    if (act5[s]) abuf[w][idx] = acc[s] * (1.0f/16.0f);
  }
  __syncthreads();

  // ---- mix: A @ W_mix[lmap], sc = h @ W_sc[lmap]
  float amv[5], scv[5];
  #pragma unroll
  for (int it = 0; it < 5; it++){
    int idx = it*64 + lane;
    amv[it] = 0.f; scv[it] = 0.f;
    if (idx < 288){
      int m = idx >> 5, d = idx & 31;
      int l = (m >= 4) ? 2 : ((m >= 1) ? 1 : 0);
      const float* wm = Wm + l*1024 + d;
      const float* ws = Ws + l*1024 + d;
      float a2 = 0.f, sc = 0.f;
      #pragma unroll
      for (int c = 0; c < 32; c++){
        a2 = fmaf(abuf[w][m*32+c], wm[c*32], a2);
        sc = fmaf(hbuf[w][m*32+c], ws[c*32], sc);
      }
      amv[it] = a2; scv[it] = sc;
    }
  }
  __syncthreads();
  #pragma unroll
  for (int it = 0; it < 5; it++){ int idx = it*64+lane; if (idx < 288) abuf[w][idx] = amv[it]; }
  __syncthreads();

  int d = lane & 31;
  float sval = abuf[w][d];
  int spec = species[n];
  float p1 = Wp1[spec*C+d], p2 = Wp2[spec*C+d], p3 = Wp3[spec*C+d];
  float f = p1 + p2*sval + p3*sval*sval;
  #pragma unroll
  for (int it = 0; it < 5; it++){
    int idx = it*64 + lane;
    if (idx < 288){
      float hn = amv[it]*f + scv[it];
      hg_out[(size_t)n*288+idx] = hn;
      hbuf[w][idx] = hn;
    }
  }
  __syncthreads();

  int g = batch[n];
  float dv0 = 0.f, dv1 = 0.f, dv2 = 0.f, ev = 0.f;
  if (lane < 32){
    dv0 = hbuf[w][32+lane]*wDv[lane];
    dv1 = hbuf[w][64+lane]*wDv[lane];
    dv2 = hbuf[w][96+lane]*wDv[lane];
  }
  if (iter == 0){
    if (lane < 32) ev = hbuf[w][lane]*wEv[lane];
  } else {
    if (lane < 16){
      float hid = 0.f;
      #pragma unroll
      for (int c = 0; c < 32; c++) hid = fmaf(hbuf[w][c], Whg[c*16+lane], hid);
      hid = silu_f(hid);
      ev = hid * wE2g[lane];
    }
  }
  #pragma unroll
  for (int off = 16; off >= 1; off >>= 1){
    ev  += __shfl_down(ev,  off);
    dv0 += __shfl_down(dv0, off);
    dv1 += __shfl_down(dv1, off);
    dv2 += __shfl_down(dv2, off);
  }
  if (lane == 0){
    atomicAdd(&glds[g][0], ev);
    atomicAdd(&glds[g][1], dv0);
    atomicAdd(&glds[g][2], dv1);
    atomicAdd(&glds[g][3], dv2);
  }
  __syncthreads();
  if (tid < NG*4){
    float v = glds[tid>>2][tid&3];
    if (v != 0.f) atomicAdd(out + tid, v);
  }
}

// ---------------------------------------------------------------- launch
extern "C" void kernel_launch(void* const* d_in, const int* in_sizes, int n_in,
                              void* d_out, int out_size, void* d_ws, size_t ws_size,
                              hipStream_t stream){
  const float* positions       = (const float*)d_in[0];
  const float* node_attrs      = (const float*)d_in[1];
  const float* charges         = (const float*)d_in[2];
  const float* atomic_energies = (const float*)d_in[3];
  const float* W_embed         = (const float*)d_in[4];
  const float* R0              = (const float*)d_in[5];
  const float* R1              = (const float*)d_in[6];
  const float* R2              = (const float*)d_in[7];
  const float* R3              = (const float*)d_in[8];
  const float* W_mix           = (const float*)d_in[9];
  const float* W_sc            = (const float*)d_in[10];
  const float* Wp1             = (const float*)d_in[11];
  const float* Wp2             = (const float*)d_in[12];
  const float* Wp3             = (const float*)d_in[13];
  const float* wE1             = (const float*)d_in[14];
  const float* wD1             = (const float*)d_in[15];
  const float* Wh              = (const float*)d_in[16];
  const float* wE2             = (const float*)d_in[17];
  const float* wD2             = (const float*)d_in[18];
  const int*   edge_index      = (const int*)d_in[19];
  const int*   batch           = (const int*)d_in[20];
  float* out = (float*)d_out;

  char* wsp = (char*)d_ws;
  float*  Ye     = (float*)wsp;  wsp += sizeof(float)*(size_t)N_EDGES*16;
  float*  Tab    = (float*)wsp;  wsp += sizeof(float)*(size_t)2*TAB_STRIDE;
  float*  hg_a   = (float*)wsp;  wsp += sizeof(float)*(size_t)N_NODES*288;
  float*  hg_b   = (float*)wsp;  wsp += sizeof(float)*(size_t)N_NODES*288;
  float4* xyzr   = (float4*)wsp; wsp += sizeof(float4)*(size_t)N_EDGES;
  float*  r_perm = (float*)wsp;  wsp += sizeof(float)*N_EDGES;
  int* counts    = (int*)wsp;    wsp += sizeof(int)*N_NODES;
  int* row_start = (int*)wsp;    wsp += sizeof(int)*(N_NODES+64);
  int* cursor    = (int*)wsp;    wsp += sizeof(int)*N_NODES;
  int* snd_perm  = (int*)wsp;    wsp += sizeof(int)*N_EDGES;
  int* species   = (int*)wsp;    wsp += sizeof(int)*N_NODES;

  hipMemsetAsync(d_out, 0, 64*sizeof(float), stream);
  hipMemsetAsync(counts, 0, N_NODES*sizeof(int), stream);
  hipMemsetAsync(hg_a, 0, sizeof(float)*(size_t)N_NODES*288, stream);

  hist_geom_kernel<<<N_EDGES/256, 256, 0, stream>>>(positions, edge_index, counts, xyzr);
  scan_kernel<<<1, 256, 0, stream>>>(counts, row_start, cursor);
  fill_geom_kernel<<<N_EDGES/256, 256, 0, stream>>>(xyzr, edge_index, cursor,
                                                    Ye, r_perm, snd_perm);
  spec_kernel<<<N_NODES/256, 256, 0, stream>>>(node_attrs, atomic_energies, charges,
                                               positions, batch, species, out);
  h0_kernel<<<N_NODES*32/256, 256, 0, stream>>>(species, W_embed, hg_a);
  table_kernel<<<2*((TABN+PPB)/PPB), 128, 0, stream>>>(R0, R1, R2, R3, Tab);

  for (int i = 0; i < 2; i++){
    const float* hin  = (i == 0) ? hg_a : hg_b;
    float*       hout = (i == 0) ? hg_b : hg_a;
    node_kernel<<<N_NODES/4, 256, 0, stream>>>(Tab + (size_t)i*TAB_STRIDE, Ye,
                                               r_perm, snd_perm, row_start,
                                               hin, hout,
                                               W_mix + i*3*C*C, W_sc + i*3*C*C,
                                               Wp1 + i*Zn*C, Wp2 + i*Zn*C, Wp3 + i*Zn*C,
                                               species, batch,
                                               wE1, (i == 0) ? wD1 : wD2,
                                               Wh, wE2, i, out);
  }
}

// Round 7
// 285.369 us; speedup vs baseline: 1.8636x; 1.0824x over previous
//
#include <hip/hip_runtime.h>
#include <math.h>

#define N_NODES 8192
#define N_EDGES 131072
#define C 32
#define Zn 10
#define NG 16
#define NB 8
#define H 64
#define TABN 4096
#define PPB 32     // table points per block
#define XS 73      // table activation LDS stride
#define NPB 8      // nodes per node_kernel block

__device__ __forceinline__ float silu_f(float v){ return v / (1.0f + __expf(-v)); }

// ================================================================ prep (fused):
// blocks [0,512): edge geometry + rcv histogram
// blocks [512,544): species + h0 row init
// blocks [544,802): radial MLP tables (both iterations, interleaved lerp pairs)
__global__ __launch_bounds__(256)
void prep_kernel(const float* __restrict__ pos, const int* __restrict__ ei,
                 int* __restrict__ counts, float4* __restrict__ xyzr,
                 const float* __restrict__ na, const float* __restrict__ Wemb,
                 int* __restrict__ species, float* __restrict__ hg,
                 const float* __restrict__ R0g, const float* __restrict__ R1g,
                 const float* __restrict__ R2g, const float* __restrict__ R3g,
                 float2* __restrict__ Tab2){
  __shared__ float xsh[PPB*XS];
  int b = blockIdx.x;
  int tid = threadIdx.x;

  if (b < 512){
    // ---- edge geometry + histogram
    int e = b*256 + tid;
    int snd = ei[e], rcv = ei[N_EDGES + e];
    float px = pos[rcv*3+0]-pos[snd*3+0];
    float py = pos[rcv*3+1]-pos[snd*3+1];
    float pz = pos[rcv*3+2]-pos[snd*3+2];
    float r = sqrtf(px*px+py*py+pz*pz + 1e-12f);
    float inv = 1.0f/r;
    xyzr[e] = make_float4(px*inv, py*inv, pz*inv, r);
    if (r < 5.0f) atomicAdd(counts + rcv, 1);
    return;
  }
  if (b < 544){
    // ---- species + h0
    int n = (b-512)*256 + tid;
    int spec = 0;
    #pragma unroll
    for (int z = 1; z < Zn; z++) if (na[n*Zn+z] > 0.5f) spec = z;
    species[n] = spec;
    float4* hrow = (float4*)(hg + (size_t)n*288);
    const float4* wrow = (const float4*)(Wemb + spec*C);
    #pragma unroll
    for (int q = 0; q < 8; q++) hrow[q] = wrow[q];
    return;
  }

  // ---- table part
  int tb = b - 544;
  const int nb = (TABN + PPB)/PPB;   // 129
  int half = tb / nb;
  int blk  = tb - half*nb;
  const float* R0i = R0g + half*NB*H;
  const float* R1i = R1g + half*H*H;
  const float* R2i = R2g + half*H*H;
  const float* R3i = R3g + half*H*96;
  float2* TabH = Tab2 + (size_t)half*((size_t)TABN*96);

  int pl = tid >> 3, jt = tid & 7;
  int i = blk*PPB + pl;
  float r = (i == 0) ? 1e-6f : (float)i * (5.0f/TABN);
  {
    float xr = r*0.2f;
    float env = 0.f;
    if (xr < 1.0f){
      float x2 = xr*xr, x5 = x2*x2*xr;
      env = 1.f - 21.f*x5 + 35.f*x5*xr - 15.f*x5*x2;
    }
    float sc = 0.6324555320336759f / r * env;
    xsh[pl*XS + jt] = sc * sinf((float)(jt+1)*0.6283185307179586f*r);
  }
  __syncthreads();

  float acc[12];
  #pragma unroll
  for (int j = 0; j < 8; j++) acc[j] = 0.f;
  #pragma unroll
  for (int k = 0; k < 8; k++){
    float xk = xsh[pl*XS + k];
    const float4* w4 = (const float4*)(R0i + k*H + jt*8);
    float4 wa = w4[0], wb = w4[1];
    acc[0]=fmaf(xk,wa.x,acc[0]); acc[1]=fmaf(xk,wa.y,acc[1]);
    acc[2]=fmaf(xk,wa.z,acc[2]); acc[3]=fmaf(xk,wa.w,acc[3]);
    acc[4]=fmaf(xk,wb.x,acc[4]); acc[5]=fmaf(xk,wb.y,acc[5]);
    acc[6]=fmaf(xk,wb.z,acc[6]); acc[7]=fmaf(xk,wb.w,acc[7]);
  }
  __syncthreads();
  #pragma unroll
  for (int j = 0; j < 8; j++) xsh[pl*XS + jt*8 + j] = silu_f(acc[j]);
  __syncthreads();

  const float* Wl[2] = {R1i, R2i};
  #pragma unroll
  for (int L = 0; L < 2; L++){
    const float* W = Wl[L];
    #pragma unroll
    for (int j = 0; j < 8; j++) acc[j] = 0.f;
    for (int k = 0; k < H; k++){
      float xk = xsh[pl*XS + k];
      const float4* w4 = (const float4*)(W + k*H + jt*8);
      float4 wa = w4[0], wb = w4[1];
      acc[0]=fmaf(xk,wa.x,acc[0]); acc[1]=fmaf(xk,wa.y,acc[1]);
      acc[2]=fmaf(xk,wa.z,acc[2]); acc[3]=fmaf(xk,wa.w,acc[3]);
      acc[4]=fmaf(xk,wb.x,acc[4]); acc[5]=fmaf(xk,wb.y,acc[5]);
      acc[6]=fmaf(xk,wb.z,acc[6]); acc[7]=fmaf(xk,wb.w,acc[7]);
    }
    __syncthreads();
    #pragma unroll
    for (int j = 0; j < 8; j++) xsh[pl*XS + jt*8 + j] = silu_f(acc[j]);
    __syncthreads();
  }

  #pragma unroll
  for (int j = 0; j < 12; j++) acc[j] = 0.f;
  for (int k = 0; k < H; k++){
    float xk = xsh[pl*XS + k];
    const float4* w4 = (const float4*)(R3i + k*96 + jt*12);
    float4 wa = w4[0], wb = w4[1], wc = w4[2];
    acc[0]=fmaf(xk,wa.x,acc[0]);  acc[1]=fmaf(xk,wa.y,acc[1]);
    acc[2]=fmaf(xk,wa.z,acc[2]);  acc[3]=fmaf(xk,wa.w,acc[3]);
    acc[4]=fmaf(xk,wb.x,acc[4]);  acc[5]=fmaf(xk,wb.y,acc[5]);
    acc[6]=fmaf(xk,wb.z,acc[6]);  acc[7]=fmaf(xk,wb.w,acc[7]);
    acc[8]=fmaf(xk,wc.x,acc[8]);  acc[9]=fmaf(xk,wc.y,acc[9]);
    acc[10]=fmaf(xk,wc.z,acc[10]); acc[11]=fmaf(xk,wc.w,acc[11]);
  }
  if (i <= TABN){
    int cb = jt*12;
    #pragma unroll
    for (int j = 0; j < 12; j++){
      int c = cb + j;
      float val = acc[j];
      if (i < TABN) TabH[(size_t)i*96 + c].x = val;      // lerp lower endpoint
      if (i > 0)    TabH[(size_t)(i-1)*96 + c].y = val;  // lerp upper endpoint
    }
  }
}

// ================================================================ scan
__global__ __launch_bounds__(256)
void scan_kernel(const int* __restrict__ counts, int* __restrict__ row_start,
                 int* __restrict__ cursor){
  __shared__ int part[256];
  int tid = threadIdx.x;
  int base = tid*32;
  int local[32];
  int s = 0;
  #pragma unroll
  for (int i = 0; i < 32; i++){ local[i] = s; s += counts[base+i]; }
  part[tid] = s; __syncthreads();
  for (int off = 1; off < 256; off <<= 1){
    int v = (tid >= off) ? part[tid-off] : 0;
    __syncthreads();
    part[tid] += v;
    __syncthreads();
  }
  int excl = part[tid] - s;
  #pragma unroll
  for (int i = 0; i < 32; i++){
    int v = excl + local[i];
    row_start[base+i] = v;
    cursor[base+i] = v;
  }
  if (tid == 255) row_start[N_NODES] = part[255];
}

// ================================================================ fill CSR slots + inline Y
__global__ __launch_bounds__(256)
void fill_geom_kernel(const float4* __restrict__ xyzr, const int* __restrict__ ei,
                      int* __restrict__ cursor, float* __restrict__ Ye,
                      float2* __restrict__ rsp){
  int e = blockIdx.x*256 + threadIdx.x;
  float4 v = xyzr[e];
  if (v.w < 5.0f){
    int rcv = ei[N_EDGES + e];
    int p = atomicAdd(cursor + rcv, 1);
    float x = v.x, y = v.y, z = v.z;
    const float s3 = 1.7320508075688772f;
    const float s5 = 2.23606797749979f;
    const float s15 = 3.872983346207417f;
    float* ye = Ye + (size_t)p*16;
    *(float4*)(ye)   = make_float4(1.f, s3*x, s3*y, s3*z);
    *(float4*)(ye+4) = make_float4(s15*x*y, s15*y*z, 0.5f*s5*(3.f*z*z-1.f), s15*x*z);
    ye[8] = 0.5f*s15*(x*x-y*y);
    rsp[p] = make_float2(v.w, __int_as_float(ei[e]));
  }
}

// ================================================================ node:
// gather (lerp table) -> slot-wave mix (transposed-weight, reg-cached) -> gate -> readout
__global__ __launch_bounds__(512)
void node_kernel(const float2* __restrict__ Tab2, const float* __restrict__ Ye,
                 const float2* __restrict__ rsp, const int* __restrict__ row_start,
                 const float* __restrict__ hg_in, float* __restrict__ hg_out,
                 const float* __restrict__ Wm_g, const float* __restrict__ Ws_g,
                 const float* __restrict__ Wp1, const float* __restrict__ Wp2,
                 const float* __restrict__ Wp3,
                 const int* __restrict__ species, const int* __restrict__ batch,
                 const float* __restrict__ ae, const float* __restrict__ charges,
                 const float* __restrict__ pos,
                 const float* __restrict__ wEv, const float* __restrict__ wDv,
                 const float* __restrict__ Whg, const float* __restrict__ wE2g,
                 int iter, float* __restrict__ out){
  __shared__ float WmT[3*32*34];      // [l][d][c], stride 34 (2-way banks, b64-aligned)
  __shared__ float WsT[3*32*34];
  __shared__ float abuf[NPB][288];    // A (gather) -> A-mixed -> h_new
  __shared__ float sbuf[NPB][288];    // sc
  __shared__ float glds[NG][4];
  int tid = threadIdx.x;
  for (int t = tid; t < 3072; t += 512){
    int l = t >> 10, rem = t & 1023, c = rem >> 5, d = rem & 31;
    WmT[(l*32+d)*34 + c] = Wm_g[t];
    WsT[(l*32+d)*34 + c] = Ws_g[t];
  }
  if (tid < NG*4) glds[tid>>2][tid&3] = 0.f;
  int w = tid >> 6, lane = tid & 63;
  int c31 = lane & 31;
  int ng0 = blockIdx.x*NPB;
  int n = ng0 + w;

  // ---- gather: A[m][c] = sum_j lerp(Tab2,r_j)[col] * h_snd[c] * Ye[j][m]
  int cols[5], ms[5]; bool act5[5];
  #pragma unroll
  for (int s = 0; s < 5; s++){
    int idx = lane + s*64;
    act5[s] = (idx < 288);
    int m = act5[s] ? (idx >> 5) : 0;
    int l = (m >= 4) ? 2 : ((m >= 1) ? 1 : 0);
    cols[s] = l*32 + (idx & 31);
    ms[s] = m;
  }
  float acc[5] = {0.f,0.f,0.f,0.f,0.f};
  int jb = row_start[n], je = row_start[n+1];
  #pragma unroll 2
  for (int j = jb; j < je; j++){
    float2 rs = rsp[j];                        // wave-uniform
    float r  = rs.x;
    int snd  = __float_as_int(rs.y);
    float u  = r * (TABN/5.0f);
    int i0   = (int)u;
    if (i0 > TABN-1) i0 = TABN-1;
    float f  = u - (float)i0;
    const float2* T2 = Tab2 + (size_t)i0*96;
    float hs = hg_in[(size_t)snd*288 + c31];
    const float* Yv = Ye + (size_t)j*16;
    #pragma unroll
    for (int s = 0; s < 5; s++){
      if (act5[s]){
        float2 tv = T2[cols[s]];
        float wv = fmaf(tv.y - tv.x, f, tv.x);
        acc[s] = fmaf(wv*hs, Yv[ms[s]], acc[s]);
      }
    }
  }
  #pragma unroll
  for (int s = 0; s < 5; s++){
    if (act5[s]) abuf[w][lane + s*64] = acc[s] * (1.0f/16.0f);
  }
  __syncthreads();

  // ---- mix: waves 0..4 each own one slot (s=w) across all 8 nodes
  float a2[NPB], scv[NPB];
  int idx0 = w*64 + lane;
  bool actm = (w < 5) && (idx0 < 288);
  if (w < 5){
    int m = idx0 >> 5; if (m > 8) m = 8;       // clamp keeps reads in-bounds
    int l = (m >= 4) ? 2 : ((m >= 1) ? 1 : 0);
    const float* wmB = WmT + (l*32 + c31)*34;
    const float* wsB = WsT + (l*32 + c31)*34;
    #pragma unroll
    for (int n2 = 0; n2 < NPB; n2++){ a2[n2] = 0.f; scv[n2] = 0.f; }
    #pragma unroll
    for (int q = 0; q < 8; q++){
      float2 wa0 = *(const float2*)(wmB + 4*q);
      float2 wa1 = *(const float2*)(wmB + 4*q + 2);
      float2 sa0 = *(const float2*)(wsB + 4*q);
      float2 sa1 = *(const float2*)(wsB + 4*q + 2);
      #pragma unroll
      for (int n2 = 0; n2 < NPB; n2++){
        float4 av = *(const float4*)(&abuf[n2][m*32 + 4*q]);
        float4 hv = *(const float4*)(hg_in + (size_t)(ng0+n2)*288 + m*32 + 4*q);
        a2[n2] = fmaf(av.x, wa0.x, a2[n2]); a2[n2] = fmaf(av.y, wa0.y, a2[n2]);
        a2[n2] = fmaf(av.z, wa1.x, a2[n2]); a2[n2] = fmaf(av.w, wa1.y, a2[n2]);
        scv[n2] = fmaf(hv.x, sa0.x, scv[n2]); scv[n2] = fmaf(hv.y, sa0.y, scv[n2]);
        scv[n2] = fmaf(hv.z, sa1.x, scv[n2]); scv[n2] = fmaf(hv.w, sa1.y, scv[n2]);
      }
    }
  }
  __syncthreads();                              // all A reads done
  if (actm){
    #pragma unroll
    for (int n2 = 0; n2 < NPB; n2++){
      abuf[n2][idx0] = a2[n2];
      sbuf[n2][idx0] = scv[n2];
    }
  }
  __syncthreads();

  // ---- gate + h write (wave w = node n)
  int spec = species[n];
  float sval = abuf[w][c31];                    // A-mixed[m=0][d]
  float p1 = Wp1[spec*C+c31], p2 = Wp2[spec*C+c31], p3 = Wp3[spec*C+c31];
  float f = p1 + p2*sval + p3*sval*sval;
  #pragma unroll
  for (int it = 0; it < 5; it++){
    int idx = it*64 + lane;
    if (idx < 288){
      float hn = abuf[w][idx]*f + sbuf[w][idx];
      hg_out[(size_t)n*288 + idx] = hn;
      abuf[w][idx] = hn;                        // same-lane RAW, wave-local
    }
  }

  // ---- readout
  int g = batch[n];
  float dv0 = 0.f, dv1 = 0.f, dv2 = 0.f, ev = 0.f;
  if (lane < 32){
    dv0 = abuf[w][32+lane]*wDv[lane];
    dv1 = abuf[w][64+lane]*wDv[lane];
    dv2 = abuf[w][96+lane]*wDv[lane];
  }
  if (iter == 0){
    if (lane < 32) ev = abuf[w][lane]*wEv[lane];
  } else {
    if (lane < 16){
      float hid = 0.f;
      #pragma unroll
      for (int c = 0; c < 32; c++) hid = fmaf(abuf[w][c], Whg[c*16+lane], hid);
      hid = silu_f(hid);
      ev = hid * wE2g[lane];
    }
  }
  #pragma unroll
  for (int off = 16; off >= 1; off >>= 1){
    ev  += __shfl_down(ev,  off);
    dv0 += __shfl_down(dv0, off);
    dv1 += __shfl_down(dv1, off);
    dv2 += __shfl_down(dv2, off);
  }
  if (lane == 0){
    if (iter == 0){                             // fold in e0 + charge-dipole baseline
      ev += ae[spec];
      float q = charges[n];
      dv0 += q*pos[n*3+0];
      dv1 += q*pos[n*3+1];
      dv2 += q*pos[n*3+2];
    }
    atomicAdd(&glds[g][0], ev);
    atomicAdd(&glds[g][1], dv0);
    atomicAdd(&glds[g][2], dv1);
    atomicAdd(&glds[g][3], dv2);
  }
  __syncthreads();
  if (tid < NG*4){
    float v = glds[tid>>2][tid&3];
    if (v != 0.f) atomicAdd(out + tid, v);
  }
}

// ================================================================ launch
extern "C" void kernel_launch(void* const* d_in, const int* in_sizes, int n_in,
                              void* d_out, int out_size, void* d_ws, size_t ws_size,
                              hipStream_t stream){
  const float* positions       = (const float*)d_in[0];
  const float* node_attrs      = (const float*)d_in[1];
  const float* charges         = (const float*)d_in[2];
  const float* atomic_energies = (const float*)d_in[3];
  const float* W_embed         = (const float*)d_in[4];
  const float* R0              = (const float*)d_in[5];
  const float* R1              = (const float*)d_in[6];
  const float* R2              = (const float*)d_in[7];
  const float* R3              = (const float*)d_in[8];
  const float* W_mix           = (const float*)d_in[9];
  const float* W_sc            = (const float*)d_in[10];
  const float* Wp1             = (const float*)d_in[11];
  const float* Wp2             = (const float*)d_in[12];
  const float* Wp3             = (const float*)d_in[13];
  const float* wE1             = (const float*)d_in[14];
  const float* wD1             = (const float*)d_in[15];
  const float* Wh              = (const float*)d_in[16];
  const float* wE2             = (const float*)d_in[17];
  const float* wD2             = (const float*)d_in[18];
  const int*   edge_index      = (const int*)d_in[19];
  const int*   batch           = (const int*)d_in[20];
  float* out = (float*)d_out;

  char* wsp = (char*)d_ws;
  float*  Ye     = (float*)wsp;  wsp += sizeof(float)*(size_t)N_EDGES*16;
  float2* Tab2   = (float2*)wsp; wsp += sizeof(float2)*(size_t)2*TABN*96;
  float*  hg_a   = (float*)wsp;  wsp += sizeof(float)*(size_t)N_NODES*288;
  float*  hg_b   = (float*)wsp;  wsp += sizeof(float)*(size_t)N_NODES*288;
  float4* xyzr   = (float4*)wsp; wsp += sizeof(float4)*(size_t)N_EDGES;
  float2* rsp    = (float2*)wsp; wsp += sizeof(float2)*(size_t)N_EDGES;
  int* counts    = (int*)wsp;    wsp += sizeof(int)*N_NODES;
  int* row_start = (int*)wsp;    wsp += sizeof(int)*(N_NODES+64);
  int* cursor    = (int*)wsp;    wsp += sizeof(int)*N_NODES;
  int* species   = (int*)wsp;    wsp += sizeof(int)*N_NODES;

  hipMemsetAsync(d_out, 0, 64*sizeof(float), stream);
  hipMemsetAsync(counts, 0, N_NODES*sizeof(int), stream);
  hipMemsetAsync(hg_a, 0, sizeof(float)*(size_t)N_NODES*288, stream);

  prep_kernel<<<802, 256, 0, stream>>>(positions, edge_index, counts, xyzr,
                                       node_attrs, W_embed, species, hg_a,
                                       R0, R1, R2, R3, Tab2);
  scan_kernel<<<1, 256, 0, stream>>>(counts, row_start, cursor);
  fill_geom_kernel<<<N_EDGES/256, 256, 0, stream>>>(xyzr, edge_index, cursor, Ye, rsp);

  for (int i = 0; i < 2; i++){
    const float* hin  = (i == 0) ? hg_a : hg_b;
    float*       hout = (i == 0) ? hg_b : hg_a;
    node_kernel<<<N_NODES/NPB, 512, 0, stream>>>(Tab2 + (size_t)i*TABN*96, Ye,
                                               rsp, row_start, hin, hout,
                                               W_mix + i*3*C*C, W_sc + i*3*C*C,
                                               Wp1 + i*Zn*C, Wp2 + i*Zn*C, Wp3 + i*Zn*C,
                                               species, batch,
                                               atomic_energies, charges, positions,
                                               wE1, (i == 0) ? wD1 : wD2,
                                               Wh, wE2, i, out);
  }
}